// Round 5
// baseline (1877.761 us; speedup 1.0000x reference)
//
#include <hip/hip_runtime.h>
#include <math.h>

#define NB 32        // batches
#define NP 512       // N == M == 512
#define RG 16        // row-groups (blocks) per batch
#define RPB 32       // rows per block
#define ITERS 50
#define EPSV   0.05f
#define INVEPS 20.0f

// ws layout in floats
#define WS_AW   0                        // [NB][NP] linear row masses (0 if masked)
#define WS_BW   (NB*NP)                  // [NB][NP] linear col masses
#define WS_HUB  (2*NB*NP)                // [64]
#define WS_S    (2*NB*NP + 64)           // [4][NB][NP] atomic-reduce buffers
#define WS_CTR  (WS_S + 4*NB*NP)         // [NB] ints

// ---- relaxed agent-scope (device-coherent, NO L2 wb/inv maintenance) ops ----
__device__ __forceinline__ void st_f32(float* p, float v) {
  __hip_atomic_store(p, v, __ATOMIC_RELAXED, __HIP_MEMORY_SCOPE_AGENT);
}
__device__ __forceinline__ float ld_f32(const float* p) {
  return __hip_atomic_load((float*)p, __ATOMIC_RELAXED, __HIP_MEMORY_SCOPE_AGENT);
}
__device__ __forceinline__ void st_i32(int* p, int v) {
  __hip_atomic_store(p, v, __ATOMIC_RELAXED, __HIP_MEMORY_SCOPE_AGENT);
}
__device__ __forceinline__ int ld_i32(const int* p) {
  return __hip_atomic_load((int*)p, __ATOMIC_RELAXED, __HIP_MEMORY_SCOPE_AGENT);
}

// ---------------- setup: aw/bw linear masses, huber, zero S/ctr/out ----------------
__global__ __launch_bounds__(NP) void setup_kernel(
    const float* __restrict__ a_mask, const float* __restrict__ pc_a,
    const float* __restrict__ b_mask, const float* __restrict__ pc_b,
    float* __restrict__ ws, float* __restrict__ out)
{
  __shared__ float scratch[16];
  const int b = blockIdx.x, t = threadIdx.x;
  const float apt = a_mask[b*NP+t] * pc_a[(b*NP+t)*3+2];
  const float bpt = b_mask[b*NP+t] * pc_b[(b*NP+t)*3+2];
  float ra = apt, rb = bpt;
  #pragma unroll
  for (int o = 32; o; o >>= 1) { ra += __shfl_xor(ra, o); rb += __shfl_xor(rb, o); }
  const int wid = t >> 6, lane = t & 63;
  if (lane == 0) { scratch[wid] = ra; scratch[8+wid] = rb; }
  __syncthreads();
  float asum = 0.f, bsum = 0.f;
  #pragma unroll
  for (int w = 0; w < 8; ++w) { asum += scratch[w]; bsum += scratch[8+w]; }

  ws[WS_AW + b*NP + t] = (apt > 0.f) ? apt/asum : 0.f;
  ws[WS_BW + b*NP + t] = (bpt > 0.f) ? bpt/bsum : 0.f;
  #pragma unroll
  for (int q = 0; q < 4; ++q)                    // zero all 4 S buffers
    ws[WS_S + ((size_t)q*NB + b)*NP + t] = 0.f;
  if (t == 0) {
    const float e = asum - bsum, ae = fabsf(e);
    ws[WS_HUB + b] = (ae <= 1.f) ? 0.5f*e*e : (ae - 0.5f);
    st_i32((int*)(ws + WS_CTR) + b, 0);
    out[b] = 0.f;
  }
}

// ---------------- main: all-linear Sinkhorn, 2 batches per block ----------------
// Block rb handles (batch b0=rb>>4, rg=rb&15) AND (batch b0+16, same rg).
// Exchange: S_t(k) = sum_blocks sum_i expK*u_i via relaxed atomicAdd into
// S[k&3][b][t]; one counter per batch gates the read. Batch interleave hides
// the MALL round-trip latency.
__global__ __launch_bounds__(NP, 2) void sinkhorn_kernel(
    const float* __restrict__ pc_a, const float* __restrict__ pc_b,
    float* __restrict__ ws, float* __restrict__ out)
{
  const int rb = blockIdx.x;
  const int rg = rb & 15;
  const int b0 = rb >> 4;            // batch pair (b0, b0+16)
  const int t  = threadIdx.x;
  const int chunk = t & 15;          // 16 threads per row
  const int lrow  = t >> 4;          // local row 0..31
  const int grow  = rg*RPB + lrow;

  float* S_base = ws + WS_S;
  int*   ctr    = (int*)(ws + WS_CTR);

  __shared__ __align__(16) float rho[2][NP];   // exp(logv) per batch (raw after loop)
  __shared__ __align__(16) float u_l[2][RPB];  // exp(logu) per batch
  __shared__ __align__(16) float sm[NP];       // epilogue reduce scratch

  float4 eKreg[2][8];     // row slice: row=grow, cols 64*cc+4*chunk+e
  float  eKcol[2][RPB];   // col slice: col=t, rows rg*32+i
  float  aw_r[2], bw_t[2], Sval[2];

  #pragma unroll
  for (int X = 0; X < 2; ++X) {
    const int b = b0 + 16*X;
    const float* aw = ws + WS_AW + (size_t)b*NP;
    const float* bw = ws + WS_BW + (size_t)b*NP;
    aw_r[X] = aw[grow];
    bw_t[X] = bw[t];
    const float ax = pc_a[((size_t)b*NP+grow)*3+0];
    const float ay = pc_a[((size_t)b*NP+grow)*3+1];
    const bool  va = aw_r[X] > 0.f;
    #pragma unroll
    for (int cc = 0; cc < 8; ++cc) {
      float r[4];
      #pragma unroll
      for (int e = 0; e < 4; ++e) {
        const int col = 64*cc + 4*chunk + e;
        const float bx = pc_b[((size_t)b*NP+col)*3+0];
        const float by = pc_b[((size_t)b*NP+col)*3+1];
        const bool  vb = bw[col] > 0.f;
        const float dx = ax-bx, dy = ay-by;
        const float d  = sqrtf(dx*dx + dy*dy + 1e-12f);
        r[e] = (va && vb) ? __expf((-INVEPS)*d) : 1.f;   // K=0 for masked pairs
      }
      eKreg[X][cc] = make_float4(r[0], r[1], r[2], r[3]);
    }
    const float bx0 = pc_b[((size_t)b*NP+t)*3+0];
    const float by0 = pc_b[((size_t)b*NP+t)*3+1];
    const bool  vb0 = bw_t[X] > 0.f;
    #pragma unroll
    for (int i = 0; i < RPB; ++i) {
      const int row = rg*RPB + i;
      const float axi = pc_a[((size_t)b*NP+row)*3+0];  // wave-uniform -> scalar loads
      const float ayi = pc_a[((size_t)b*NP+row)*3+1];
      const bool  vai = aw[row] > 0.f;
      const float dx = axi-bx0, dy = ayi-by0;
      const float d  = sqrtf(dx*dx + dy*dy + 1e-12f);
      eKcol[X][i] = (vai && vb0) ? __expf((-INVEPS)*d) : 1.f;
    }
    Sval[X] = 0.f;
  }

  for (int k = 1; k <= ITERS; ++k) {
    #pragma unroll
    for (int X = 0; X < 2; ++X) {
      const int b = b0 + 16*X;
      // ---- A: rho_t = bw_t / S_t(k-1)   (k==1: logv=0 -> rho=1 for ALL cols)
      rho[X][t] = (k == 1) ? 1.f : bw_t[X] / fmaxf(Sval[X], 1e-38f);
      __syncthreads();
      // ---- B: dot_i = sum_j ek*rho_j (shfl-reduce over the 16 lanes of the row)
      const float4* r4p = (const float4*)rho[X];
      float dot = 0.f;
      #pragma unroll
      for (int cc = 0; cc < 8; ++cc) {
        const float4 g4 = r4p[16*cc + chunk];
        const float4 kk = eKreg[X][cc];
        dot += kk.x*g4.x + kk.y*g4.y + kk.z*g4.z + kk.w*g4.w;
      }
      #pragma unroll
      for (int o = 8; o; o >>= 1) dot += __shfl_xor(dot, o);
      const float u = aw_r[X] / fmaxf(dot, 1e-38f);     // exp(logu), 0 for masked rows
      if (chunk == 0) u_l[X][lrow] = u;
      __syncthreads();
      // ---- C: s_col = sum_i ek*u_i, atomic-reduce across the 16 blocks
      const float4* u4p = (const float4*)u_l[X];
      float sc = 0.f;
      #pragma unroll
      for (int i4 = 0; i4 < 8; ++i4) {
        const float4 uu = u4p[i4];
        sc += eKcol[X][4*i4+0]*uu.x + eKcol[X][4*i4+1]*uu.y
            + eKcol[X][4*i4+2]*uu.z + eKcol[X][4*i4+3]*uu.w;
      }
      __hip_atomic_fetch_add(S_base + ((size_t)(k & 3)*NB + b)*NP + t, sc,
                             __ATOMIC_RELAXED, __HIP_MEMORY_SCOPE_AGENT);
      __syncthreads();   // drains vmcnt -> all adds ack'd at coherence point
      if (t == 0) __hip_atomic_fetch_add(&ctr[b], 1, __ATOMIC_RELAXED, __HIP_MEMORY_SCOPE_AGENT);
    }
    // ---- poll + load + rotate-zero (no barrier needed: per-thread data)
    #pragma unroll
    for (int X = 0; X < 2; ++X) {
      const int b = b0 + 16*X;
      const int target = RG * k;
      long long spins = 0;
      while (ld_i32(&ctr[b]) < target) {
        __builtin_amdgcn_s_sleep(4);
        if (++spins > (1LL<<28)) break;   // fail visibly, never hang
      }
      Sval[X] = ld_f32(S_base + ((size_t)(k & 3)*NB + b)*NP + t);
      // zero buffer (k+3)&3 == (k-1)&3: last read at poll(k-1) (done, ctr>=16k);
      // next adds at C(k+3), gated >= 2 full iterations after every poll(k).
      if ((t >> 5) == rg)
        st_f32(S_base + ((size_t)((k+3) & 3)*NB + b)*NP + t, 0.f);
    }
  }

  // ---- epilogue: flow_ij = u_i * ek_ij * vraw_j ; ot = sum d^2 * flow
  #pragma unroll
  for (int X = 0; X < 2; ++X)
    rho[X][t] = bw_t[X] / fmaxf(Sval[X], 1e-38f);   // raw exp(logv(50))
  __syncthreads();

  #pragma unroll
  for (int X = 0; X < 2; ++X) {
    const int b = b0 + 16*X;
    const float ur = u_l[X][lrow];                  // exp(logu(50))
    const float4* r4p = (const float4*)rho[X];
    float acc = 0.f;
    #pragma unroll
    for (int cc = 0; cc < 8; ++cc) {
      const float4 g4 = r4p[16*cc + chunk];
      const float4 kk = eKreg[X][cc];
      const float ek[4] = {kk.x, kk.y, kk.z, kk.w};
      const float vv[4] = {g4.x, g4.y, g4.z, g4.w};
      #pragma unroll
      for (int e = 0; e < 4; ++e) {
        const float lk = __logf(fmaxf(ek[e], 1e-38f));  // d = -EPS*lk; masked: lk=0
        const float d2 = (EPSV*lk)*(EPSV*lk);
        const float v  = d2 * ur * ek[e] * vv[e];
        acc += (ek[e] > 0.f) ? v : 0.f;
      }
    }
    sm[t] = acc;
    __syncthreads();
    if (t < 64) {
      float v = 0.f;
      #pragma unroll
      for (int q = 0; q < 8; ++q) v += sm[t*8+q];
      #pragma unroll
      for (int o = 32; o; o >>= 1) v += __shfl_xor(v, o);
      if (t == 0) {
        const float add = v + ((rg == 0) ? (ws + WS_HUB)[b] : 0.f);
        atomicAdd(&out[b], add);
      }
    }
    __syncthreads();   // before reusing sm for the second batch
  }
}

extern "C" void kernel_launch(void* const* d_in, const int* in_sizes, int n_in,
                              void* d_out, int out_size, void* d_ws, size_t ws_size,
                              hipStream_t stream) {
  const float* a_mask = (const float*)d_in[0];
  const float* pc_a   = (const float*)d_in[1];
  const float* b_mask = (const float*)d_in[2];
  const float* pc_b   = (const float*)d_in[3];
  float* out = (float*)d_out;
  float* ws  = (float*)d_ws;
  (void)in_sizes; (void)n_in; (void)out_size; (void)ws_size;

  setup_kernel<<<NB, NP, 0, stream>>>(a_mask, pc_a, b_mask, pc_b, ws, out);
  sinkhorn_kernel<<<NB*RG/2, NP, 0, stream>>>(pc_a, pc_b, ws, out);
}

// Round 6
// 524.307 us; speedup vs baseline: 3.5814x; 3.5814x over previous
//
#include <hip/hip_runtime.h>
#include <math.h>

#define NB 32        // batches
#define NP 512       // N == M == 512
#define RG 16        // row-groups (blocks) per batch
#define RPB 32       // rows per block
#define ITERS 50
#define EPSV   0.05f
#define INVEPS 20.0f

typedef unsigned long long u64;

// ws layout (float2): parts[2][NB][RG][NP], then epi[NB][RG].
// No init pass needed: harness poison 0xAAAAAAAA as float = -3.03e-13 can never
// equal a valid tag float (1..51), so tag-gated reads are poison-safe.
#define N_PARTS (2*NB*RG*NP)

// ---- relaxed agent-scope tagged 8B exchange: tag+value arrive atomically ----
__device__ __forceinline__ void st64(float2* p, float tag, float val) {
  union { float2 f; u64 u; } c; c.f = make_float2(tag, val);
  __hip_atomic_store((u64*)p, c.u, __ATOMIC_RELAXED, __HIP_MEMORY_SCOPE_AGENT);
}
__device__ __forceinline__ float2 ld64(const float2* p) {
  union { u64 u; float2 f; } c;
  c.u = __hip_atomic_load((const u64*)p, __ATOMIC_RELAXED, __HIP_MEMORY_SCOPE_AGENT);
  return c.f;
}

// ---------------- single fused kernel: setup + 50 linear-Sinkhorn iters + ot ----------------
// Block rb: rg = rb&15, handles batches b0=rb>>4 and b0+16 (interleaved).
// Exchange: each thread publishes {tag=k, s_col} (single-writer slots); readers
// poll tags directly — flag fused into data, no RMW, no separate barrier.
__global__ __launch_bounds__(NP, 2) void emd_kernel(
    const float* __restrict__ a_mask, const float* __restrict__ pc_a,
    const float* __restrict__ b_mask, const float* __restrict__ pc_b,
    float2* __restrict__ parts, float2* __restrict__ epi,
    float* __restrict__ out)
{
  const int rb = blockIdx.x;
  const int rg = rb & 15;
  const int b0 = rb >> 4;            // batch pair (b0, b0+16)
  const int t  = threadIdx.x;
  const int chunk = t & 15;          // 16 threads per row
  const int lrow  = t >> 4;          // local row 0..31
  const int grow  = rg*RPB + lrow;
  const int lane  = t & 63, wid = t >> 6;

  __shared__ __align__(16) float rho[2][NP];   // exp(logv); bw_l during setup
  __shared__ __align__(16) float u_l[2][RPB];  // exp(logu)
  __shared__ __align__(16) float sm[NP];       // aw_l during setup; reduce scratch
  __shared__ float red[16];

  float4 eKreg[2][8];     // row slice: row=grow, cols 64*cc+4*chunk+e
  float  eKcol[2][RPB];   // col slice: col=t, rows rg*32+i
  float  aw_r[2], bw_t[2];
  float  hub0 = 0.f, hub1 = 0.f;

  // ================= setup: masses, huber, expK caches =================
  #pragma unroll
  for (int X = 0; X < 2; ++X) {
    const int b = b0 + 16*X;
    const float apt = a_mask[b*NP+t] * pc_a[((size_t)b*NP+t)*3+2];
    const float bpt = b_mask[b*NP+t] * pc_b[((size_t)b*NP+t)*3+2];
    float ra = apt, rv = bpt;
    #pragma unroll
    for (int o = 32; o; o >>= 1) { ra += __shfl_xor(ra, o); rv += __shfl_xor(rv, o); }
    if (lane == 0) { red[wid] = ra; red[8+wid] = rv; }
    __syncthreads();
    float asum = 0.f, bsum = 0.f;
    #pragma unroll
    for (int w = 0; w < 8; ++w) { asum += red[w]; bsum += red[8+w]; }
    const float e = asum - bsum, ae = fabsf(e);
    const float hub = (ae <= 1.f) ? 0.5f*e*e : (ae - 0.5f);
    if (X == 0) hub0 = hub; else hub1 = hub;
    sm[t]     = (apt > 0.f) ? apt/asum : 0.f;   // aw_l
    rho[X][t] = (bpt > 0.f) ? bpt/bsum : 0.f;   // bw_l (temp)
    __syncthreads();
    aw_r[X] = sm[grow];
    bw_t[X] = rho[X][t];
    const float ax = pc_a[((size_t)b*NP+grow)*3+0];
    const float ay = pc_a[((size_t)b*NP+grow)*3+1];
    const bool  va = aw_r[X] > 0.f;
    #pragma unroll
    for (int cc = 0; cc < 8; ++cc) {
      float r[4];
      #pragma unroll
      for (int e2 = 0; e2 < 4; ++e2) {
        const int col = 64*cc + 4*chunk + e2;
        const float bx = pc_b[((size_t)b*NP+col)*3+0];
        const float by = pc_b[((size_t)b*NP+col)*3+1];
        const bool  vb = rho[X][col] > 0.f;
        const float dx = ax-bx, dy = ay-by;
        const float d  = sqrtf(dx*dx + dy*dy + 1e-12f);
        r[e2] = (va && vb) ? __expf((-INVEPS)*d) : 1.f;   // K=0 for masked pairs
      }
      eKreg[X][cc] = make_float4(r[0], r[1], r[2], r[3]);
    }
    const float bx0 = pc_b[((size_t)b*NP+t)*3+0];
    const float by0 = pc_b[((size_t)b*NP+t)*3+1];
    const bool  vb0 = bw_t[X] > 0.f;
    #pragma unroll
    for (int i = 0; i < RPB; ++i) {
      const int row = rg*RPB + i;
      const float axi = pc_a[((size_t)b*NP+row)*3+0];  // wave-uniform -> scalar loads
      const float ayi = pc_a[((size_t)b*NP+row)*3+1];
      const bool  vai = sm[row] > 0.f;
      const float dx = axi-bx0, dy = ayi-by0;
      const float d  = sqrtf(dx*dx + dy*dy + 1e-12f);
      eKcol[X][i] = (vai && vb0) ? __expf((-INVEPS)*d) : 1.f;
    }
    __syncthreads();   // sm/red/rho[X] reuse safety for next X
  }

  // ================= main loop =================
  for (int k = 1; k <= ITERS; ++k) {
    // ---- A: rho(k-1) from tagged partials (k==1: logv=0 -> rho=1)
    if (k == 1) {
      rho[0][t] = 1.f; rho[1][t] = 1.f;
    } else {
      const float tagf = (float)(k-1);
      const int par = (k-1) & 1;
      float2 pr[2][RG];
      #pragma unroll
      for (int X = 0; X < 2; ++X) {
        const float2* base = parts + (((size_t)par*NB + (b0+16*X))*RG)*NP + t;
        #pragma unroll
        for (int r = 0; r < RG; ++r) pr[X][r] = ld64(base + (size_t)r*NP);  // 32 loads in flight
      }
      #pragma unroll
      for (int X = 0; X < 2; ++X) {
        const float2* base = parts + (((size_t)par*NB + (b0+16*X))*RG)*NP + t;
        #pragma unroll
        for (int r = 0; r < RG; ++r) {
          long long spins = 0;
          while (pr[X][r].x != tagf) {               // straggler re-poll
            __builtin_amdgcn_s_sleep(1);
            pr[X][r] = ld64(base + (size_t)r*NP);
            if (++spins > (1LL<<27)) break;          // fail visibly, never hang
          }
        }
        float S = 0.f;
        #pragma unroll
        for (int r = 0; r < RG; ++r) S += pr[X][r].y;
        rho[X][t] = bw_t[X] / fmaxf(S, 1e-38f);
      }
    }
    __syncthreads();

    // ---- B: row dots u(k) = aw / sum_j ek*rho_j
    #pragma unroll
    for (int X = 0; X < 2; ++X) {
      const float4* r4p = (const float4*)rho[X];
      float dot = 0.f;
      #pragma unroll
      for (int cc = 0; cc < 8; ++cc) {
        const float4 g4 = r4p[16*cc + chunk];
        const float4 kk = eKreg[X][cc];
        dot += kk.x*g4.x + kk.y*g4.y + kk.z*g4.z + kk.w*g4.w;
      }
      #pragma unroll
      for (int o = 8; o; o >>= 1) dot += __shfl_xor(dot, o);   // 16-lane row reduce
      if (chunk == 0) u_l[X][lrow] = aw_r[X] / fmaxf(dot, 1e-38f);
    }
    __syncthreads();

    // ---- C: col partials s_col = sum_i ek*u_i, published with tag=k
    {
      const float tagk = (float)k;
      const int par = k & 1;
      #pragma unroll
      for (int X = 0; X < 2; ++X) {
        const float4* u4p = (const float4*)u_l[X];
        float sc = 0.f;
        #pragma unroll
        for (int i4 = 0; i4 < 8; ++i4) {
          const float4 uu = u4p[i4];
          sc += eKcol[X][4*i4+0]*uu.x + eKcol[X][4*i4+1]*uu.y
              + eKcol[X][4*i4+2]*uu.z + eKcol[X][4*i4+3]*uu.w;
        }
        st64(parts + (((size_t)par*NB + (b0+16*X))*RG + rg)*NP + t, tagk, sc);
      }
    }
    // no barrier needed: A(k+1) writes rho only after B(k)'s barrier; slots are
    // single-writer; readers self-synchronize on tags.
  }

  // ---- final combine: rho(50) ----
  {
    const float tagf = (float)ITERS;
    const int par = ITERS & 1;
    #pragma unroll
    for (int X = 0; X < 2; ++X) {
      const float2* base = parts + (((size_t)par*NB + (b0+16*X))*RG)*NP + t;
      float2 pr[RG];
      #pragma unroll
      for (int r = 0; r < RG; ++r) pr[r] = ld64(base + (size_t)r*NP);
      #pragma unroll
      for (int r = 0; r < RG; ++r) {
        long long spins = 0;
        while (pr[r].x != tagf) {
          __builtin_amdgcn_s_sleep(1);
          pr[r] = ld64(base + (size_t)r*NP);
          if (++spins > (1LL<<27)) break;
        }
      }
      float S = 0.f;
      #pragma unroll
      for (int r = 0; r < RG; ++r) S += pr[r].y;
      rho[X][t] = bw_t[X] / fmaxf(S, 1e-38f);
    }
  }
  __syncthreads();

  // ---- epilogue: ot partial = sum d^2 * u_i * ek * rho_j over my row slice
  float accX[2];
  #pragma unroll
  for (int X = 0; X < 2; ++X) {
    const float ur = u_l[X][lrow];
    const float4* r4p = (const float4*)rho[X];
    float acc = 0.f;
    #pragma unroll
    for (int cc = 0; cc < 8; ++cc) {
      const float4 g4 = r4p[16*cc + chunk];
      const float4 kk = eKreg[X][cc];
      const float ek[4] = {kk.x, kk.y, kk.z, kk.w};
      const float vv[4] = {g4.x, g4.y, g4.z, g4.w};
      #pragma unroll
      for (int e2 = 0; e2 < 4; ++e2) {
        const float lk = __logf(fmaxf(ek[e2], 1e-38f));  // d = -EPS*lk; masked: lk=0 -> d2=0
        const float d2 = (EPSV*lk)*(EPSV*lk);
        const float v  = d2 * ur * ek[e2] * vv[e2];
        acc += (ek[e2] > 0.f) ? v : 0.f;
      }
    }
    accX[X] = acc;
  }
  // block-reduce each batch, publish tagged epi, rg==0 gathers (no atomics, no init)
  float s0 = 0.f, s1 = 0.f;
  sm[t] = accX[0];
  __syncthreads();
  if (t < 64) {
    float v = 0.f;
    #pragma unroll
    for (int q = 0; q < 8; ++q) v += sm[t*8+q];
    #pragma unroll
    for (int o = 32; o; o >>= 1) v += __shfl_xor(v, o);
    s0 = v;
  }
  __syncthreads();
  sm[t] = accX[1];
  __syncthreads();
  if (t < 64) {
    float v = 0.f;
    #pragma unroll
    for (int q = 0; q < 8; ++q) v += sm[t*8+q];
    #pragma unroll
    for (int o = 32; o; o >>= 1) v += __shfl_xor(v, o);
    s1 = v;
  }
  if (t == 0) {
    st64(epi + (size_t)b0*RG + rg,        51.f, s0);
    st64(epi + (size_t)(b0+16)*RG + rg,   51.f, s1);
  }
  if (rg == 0 && t < 32) {     // gather: 16 lanes per batch, poll + shfl-reduce
    const int X = t >> 4, r = t & 15;
    const int b = b0 + 16*X;
    float2 pr;
    long long spins = 0;
    do {
      pr = ld64(epi + (size_t)b*RG + r);
      if (pr.x == 51.f) break;
      __builtin_amdgcn_s_sleep(1);
    } while (++spins < (1LL<<27));
    float v = pr.y;
    #pragma unroll
    for (int o = 8; o; o >>= 1) v += __shfl_xor(v, o);
    if (r == 0) out[b] = v + ((X == 0) ? hub0 : hub1);
  }
}

extern "C" void kernel_launch(void* const* d_in, const int* in_sizes, int n_in,
                              void* d_out, int out_size, void* d_ws, size_t ws_size,
                              hipStream_t stream) {
  const float* a_mask = (const float*)d_in[0];
  const float* pc_a   = (const float*)d_in[1];
  const float* b_mask = (const float*)d_in[2];
  const float* pc_b   = (const float*)d_in[3];
  float* out = (float*)d_out;
  float2* parts = (float2*)d_ws;            // 4 MiB
  float2* epi   = parts + N_PARTS;          // + 4 KiB
  (void)in_sizes; (void)n_in; (void)out_size; (void)ws_size;

  emd_kernel<<<NB*RG/2, NP, 0, stream>>>(a_mask, pc_a, b_mask, pc_b, parts, epi, out);
}

// Round 7
// 330.420 us; speedup vs baseline: 5.6829x; 1.5868x over previous
//
#include <hip/hip_runtime.h>
#include <math.h>

#define NB 32        // batches
#define NP 512       // N == M == 512
#define RG 16        // row-groups (blocks) per batch
#define RPB 32       // rows per block
#define ITERS 50
#define EPSV   0.05f
#define INVEPS 20.0f

typedef unsigned long long u64;

// ws layout (float2): parts[2][NB][RG][NP], rhob[2][NB][NP], epi[NB][RG].
// No init pass: harness poison 0xAAAAAAAA as float (-3.03e-13) never equals a
// valid tag float (1..51), so tag-gated reads are poison-safe.
#define N_PARTS (2*NB*RG*NP)
#define N_RHOB  (2*NB*NP)

// ---- relaxed agent-scope tagged 8B exchange: tag+value arrive atomically ----
__device__ __forceinline__ void st64(float2* p, float tag, float val) {
  union { float2 f; u64 u; } c; c.f = make_float2(tag, val);
  __hip_atomic_store((u64*)p, c.u, __ATOMIC_RELAXED, __HIP_MEMORY_SCOPE_AGENT);
}
__device__ __forceinline__ float2 ld64(const float2* p) {
  union { u64 u; float2 f; } c;
  c.u = __hip_atomic_load((const u64*)p, __ATOMIC_RELAXED, __HIP_MEMORY_SCOPE_AGENT);
  return c.f;
}

// ---------------- single fused kernel: setup + 50 linear-Sinkhorn iters + ot ----
// Block rb: rg = rb&15, batches b0=rb>>4 and b0+16 (interleaved).
// Per iter: B u=aw/(eK·rho) [local] -> C publish tagged col-partials ->
// combine: this block reduces column slice [32rg,32rg+32) of its batches
// (each partial entry read ONCE device-wide) and publishes tagged rho ->
// A: 1 tagged rho load per thread per batch. 4 coherent loads/thread/iter.
__global__ __launch_bounds__(NP, 2) void emd_kernel(
    const float* __restrict__ a_mask, const float* __restrict__ pc_a,
    const float* __restrict__ b_mask, const float* __restrict__ pc_b,
    float2* __restrict__ parts, float2* __restrict__ rhob,
    float2* __restrict__ epi, float* __restrict__ out)
{
  const int rb = blockIdx.x;
  const int rg = rb & 15;
  const int b0 = rb >> 4;            // batch pair (b0, b0+16)
  const int t  = threadIdx.x;
  const int chunk = t & 15;          // 16 threads per row
  const int lrow  = t >> 4;          // local row 0..31
  const int grow  = rg*RPB + lrow;
  const int lane  = t & 63, wid = t >> 6;
  const int r_st  = t & 15;          // combine: stream index
  const int c_l   = t >> 4;          // combine: col within slice (0..31)
  const int gcol  = 32*rg + c_l;     // combine: global col

  __shared__ __align__(16) float rho_l[2][NP];  // exp(logv)
  __shared__ __align__(16) float bw_l[2][NP];   // col masses
  __shared__ __align__(16) float u_l[2][RPB];   // exp(logu)
  __shared__ __align__(16) float sm[NP];        // setup aw / epilogue scratch
  __shared__ float red[16];

  float4 eKreg[2][8];     // row slice: row=grow, cols 64*cc+4*chunk+e
  float  eKcol[2][RPB];   // col slice: col=t, rows rg*32+i
  float  aw_r[2], bw_t[2];
  float  hub0 = 0.f, hub1 = 0.f;

  // ================= setup: masses, huber, expK caches =================
  #pragma unroll
  for (int X = 0; X < 2; ++X) {
    const int b = b0 + 16*X;
    const float apt = a_mask[b*NP+t] * pc_a[((size_t)b*NP+t)*3+2];
    const float bpt = b_mask[b*NP+t] * pc_b[((size_t)b*NP+t)*3+2];
    float ra = apt, rv = bpt;
    #pragma unroll
    for (int o = 32; o; o >>= 1) { ra += __shfl_xor(ra, o); rv += __shfl_xor(rv, o); }
    if (lane == 0) { red[wid] = ra; red[8+wid] = rv; }
    __syncthreads();
    float asum = 0.f, bsum = 0.f;
    #pragma unroll
    for (int w = 0; w < 8; ++w) { asum += red[w]; bsum += red[8+w]; }
    const float e = asum - bsum, ae = fabsf(e);
    const float hub = (ae <= 1.f) ? 0.5f*e*e : (ae - 0.5f);
    if (X == 0) hub0 = hub; else hub1 = hub;
    sm[t]      = (apt > 0.f) ? apt/asum : 0.f;   // aw
    bw_l[X][t] = (bpt > 0.f) ? bpt/bsum : 0.f;
    __syncthreads();
    aw_r[X] = sm[grow];
    bw_t[X] = bw_l[X][t];
    const float ax = pc_a[((size_t)b*NP+grow)*3+0];
    const float ay = pc_a[((size_t)b*NP+grow)*3+1];
    const bool  va = aw_r[X] > 0.f;
    #pragma unroll
    for (int cc = 0; cc < 8; ++cc) {
      float r[4];
      #pragma unroll
      for (int e2 = 0; e2 < 4; ++e2) {
        const int col = 64*cc + 4*chunk + e2;
        const float bx = pc_b[((size_t)b*NP+col)*3+0];
        const float by = pc_b[((size_t)b*NP+col)*3+1];
        const bool  vb = bw_l[X][col] > 0.f;
        const float dx = ax-bx, dy = ay-by;
        const float d  = sqrtf(dx*dx + dy*dy + 1e-12f);
        r[e2] = (va && vb) ? __expf((-INVEPS)*d) : 1.f;   // K=0 for masked pairs
      }
      eKreg[X][cc] = make_float4(r[0], r[1], r[2], r[3]);
    }
    const float bx0 = pc_b[((size_t)b*NP+t)*3+0];
    const float by0 = pc_b[((size_t)b*NP+t)*3+1];
    const bool  vb0 = bw_t[X] > 0.f;
    #pragma unroll
    for (int i = 0; i < RPB; ++i) {
      const int row = rg*RPB + i;
      const float axi = pc_a[((size_t)b*NP+row)*3+0];  // wave-uniform -> scalar loads
      const float ayi = pc_a[((size_t)b*NP+row)*3+1];
      const bool  vai = sm[row] > 0.f;
      const float dx = axi-bx0, dy = ayi-by0;
      const float d  = sqrtf(dx*dx + dy*dy + 1e-12f);
      eKcol[X][i] = (vai && vb0) ? __expf((-INVEPS)*d) : 1.f;
    }
    rho_l[X][t] = 1.f;     // rho(0) = exp(logv=0) = 1
    __syncthreads();       // sm/red reuse safety + rho_l ready
  }

  // ================= main loop =================
  for (int k = 1; k <= ITERS; ++k) {
    const float tagk = (float)k;
    const int par = k & 1;

    // ---- B: u(k) = aw / sum_j ek*rho(k-1)   (local)
    #pragma unroll
    for (int X = 0; X < 2; ++X) {
      const float4* r4p = (const float4*)rho_l[X];
      float dot = 0.f;
      #pragma unroll
      for (int cc = 0; cc < 8; ++cc) {
        const float4 g4 = r4p[16*cc + chunk];
        const float4 kk = eKreg[X][cc];
        dot += kk.x*g4.x + kk.y*g4.y + kk.z*g4.z + kk.w*g4.w;
      }
      #pragma unroll
      for (int o = 8; o; o >>= 1) dot += __shfl_xor(dot, o);   // 16-lane row reduce
      if (chunk == 0) u_l[X][lrow] = aw_r[X] / fmaxf(dot, 1e-38f);
    }
    __syncthreads();   // u_l ready (also: all rho_l reads of this iter done)

    // ---- C: publish tagged col partials s(k)
    #pragma unroll
    for (int X = 0; X < 2; ++X) {
      const float4* u4p = (const float4*)u_l[X];
      float sc = 0.f;
      #pragma unroll
      for (int i4 = 0; i4 < 8; ++i4) {
        const float4 uu = u4p[i4];
        sc += eKcol[X][4*i4+0]*uu.x + eKcol[X][4*i4+1]*uu.y
            + eKcol[X][4*i4+2]*uu.z + eKcol[X][4*i4+3]*uu.w;
      }
      st64(parts + (((size_t)par*NB + (b0+16*X))*RG + rg)*NP + t, tagk, sc);
    }

    // ---- combine: reduce slice [32rg,32rg+32) for both batches, publish rho(k)
    {
      float2 q[2];
      #pragma unroll
      for (int X = 0; X < 2; ++X)    // issue both loads before polling
        q[X] = ld64(parts + (((size_t)par*NB + (b0+16*X))*RG + r_st)*NP + gcol);
      #pragma unroll
      for (int X = 0; X < 2; ++X) {
        const float2* slot = parts + (((size_t)par*NB + (b0+16*X))*RG + r_st)*NP + gcol;
        long long spins = 0;
        while (q[X].x != tagk) {
          __builtin_amdgcn_s_sleep(1);
          q[X] = ld64(slot);
          if (++spins > (1LL<<27)) break;   // fail visibly, never hang
        }
        float S = q[X].y;
        #pragma unroll
        for (int o = 8; o; o >>= 1) S += __shfl_xor(S, o);     // over 16 streams
        if (r_st == 0) {
          const float rho = bw_l[X][gcol] / fmaxf(S, 1e-38f);
          st64(rhob + ((size_t)par*NB + (b0+16*X))*NP + gcol, tagk, rho);
        }
      }
    }

    // ---- A: poll rho(k), 1 load per thread per batch
    {
      float2 rq[2];
      #pragma unroll
      for (int X = 0; X < 2; ++X)
        rq[X] = ld64(rhob + ((size_t)par*NB + (b0+16*X))*NP + t);
      #pragma unroll
      for (int X = 0; X < 2; ++X) {
        const float2* slot = rhob + ((size_t)par*NB + (b0+16*X))*NP + t;
        long long spins = 0;
        while (rq[X].x != tagk) {
          __builtin_amdgcn_s_sleep(1);
          rq[X] = ld64(slot);
          if (++spins > (1LL<<27)) break;
        }
        rho_l[X][t] = rq[X].y;
      }
    }
    __syncthreads();   // rho_l(k) ready for B(k+1) / epilogue
  }

  // ---- epilogue: ot partial = sum d^2 * u_i * ek * rho_j over my row slice
  float accX[2];
  #pragma unroll
  for (int X = 0; X < 2; ++X) {
    const float ur = u_l[X][lrow];                  // u(50)
    const float4* r4p = (const float4*)rho_l[X];    // rho(50)
    float acc = 0.f;
    #pragma unroll
    for (int cc = 0; cc < 8; ++cc) {
      const float4 g4 = r4p[16*cc + chunk];
      const float4 kk = eKreg[X][cc];
      const float ek[4] = {kk.x, kk.y, kk.z, kk.w};
      const float vv[4] = {g4.x, g4.y, g4.z, g4.w};
      #pragma unroll
      for (int e2 = 0; e2 < 4; ++e2) {
        const float lk = __logf(fmaxf(ek[e2], 1e-38f));  // d = -EPS*lk; masked: lk=0 -> d2=0
        const float d2 = (EPSV*lk)*(EPSV*lk);
        const float v  = d2 * ur * ek[e2] * vv[e2];
        acc += (ek[e2] > 0.f) ? v : 0.f;
      }
    }
    accX[X] = acc;
  }
  // block-reduce each batch, publish tagged epi, rg==0 gathers
  float s0 = 0.f, s1 = 0.f;
  sm[t] = accX[0];
  __syncthreads();
  if (t < 64) {
    float v = 0.f;
    #pragma unroll
    for (int q = 0; q < 8; ++q) v += sm[t*8+q];
    #pragma unroll
    for (int o = 32; o; o >>= 1) v += __shfl_xor(v, o);
    s0 = v;
  }
  __syncthreads();
  sm[t] = accX[1];
  __syncthreads();
  if (t < 64) {
    float v = 0.f;
    #pragma unroll
    for (int q = 0; q < 8; ++q) v += sm[t*8+q];
    #pragma unroll
    for (int o = 32; o; o >>= 1) v += __shfl_xor(v, o);
    s1 = v;
  }
  if (t == 0) {
    st64(epi + (size_t)b0*RG + rg,      51.f, s0);
    st64(epi + (size_t)(b0+16)*RG + rg, 51.f, s1);
  }
  if (rg == 0 && t < 32) {     // gather: 16 lanes per batch, poll + shfl-reduce
    const int X = t >> 4, r = t & 15;
    const int b = b0 + 16*X;
    float2 pr;
    long long spins = 0;
    do {
      pr = ld64(epi + (size_t)b*RG + r);
      if (pr.x == 51.f) break;
      __builtin_amdgcn_s_sleep(1);
    } while (++spins < (1LL<<27));
    float v = pr.y;
    #pragma unroll
    for (int o = 8; o; o >>= 1) v += __shfl_xor(v, o);
    if (r == 0) out[b] = v + ((X == 0) ? hub0 : hub1);
  }
}

extern "C" void kernel_launch(void* const* d_in, const int* in_sizes, int n_in,
                              void* d_out, int out_size, void* d_ws, size_t ws_size,
                              hipStream_t stream) {
  const float* a_mask = (const float*)d_in[0];
  const float* pc_a   = (const float*)d_in[1];
  const float* b_mask = (const float*)d_in[2];
  const float* pc_b   = (const float*)d_in[3];
  float* out = (float*)d_out;
  float2* parts = (float2*)d_ws;            // 4 MiB
  float2* rhob  = parts + N_PARTS;          // + 256 KiB
  float2* epi   = rhob + N_RHOB;            // + 4 KiB
  (void)in_sizes; (void)n_in; (void)out_size; (void)ws_size;

  emd_kernel<<<NB*RG/2, NP, 0, stream>>>(a_mask, pc_a, b_mask, pc_b,
                                         parts, rhob, epi, out);
}

// Round 8
// 274.134 us; speedup vs baseline: 6.8498x; 1.2053x over previous
//
#include <hip/hip_runtime.h>
#include <math.h>

#define NB 32        // batches
#define NP 512       // N == M == 512
#define RG 16        // row-groups (blocks) per batch
#define RPB 32       // rows per block
#define ITERS 50
#define EPSV   0.05f
#define INVEPS 20.0f

typedef unsigned long long u64;

// ws layout (float2): parts[2][NB][RG][NP], rhob[2][NB][NP], epi[NB][RG].
// No init pass: harness poison 0xAAAAAAAA as float (-3.03e-13) never equals a
// valid tag float (1..51), so tag-gated reads are poison-safe.
#define N_PARTS (2*NB*RG*NP)
#define N_RHOB  (2*NB*NP)

// ---- relaxed agent-scope tagged 8B exchange: tag+value arrive atomically ----
__device__ __forceinline__ void st64(float2* p, float tag, float val) {
  union { float2 f; u64 u; } c; c.f = make_float2(tag, val);
  __hip_atomic_store((u64*)p, c.u, __ATOMIC_RELAXED, __HIP_MEMORY_SCOPE_AGENT);
}
__device__ __forceinline__ float2 ld64(const float2* p) {
  union { u64 u; float2 f; } c;
  c.u = __hip_atomic_load((const u64*)p, __ATOMIC_RELAXED, __HIP_MEMORY_SCOPE_AGENT);
  return c.f;
}

// ---------------- single fused kernel: setup + 50 linear-Sinkhorn iters + ot ----
// Block rb: rg = rb&15, batches b0=rb>>4 and b0+16, batch 1 half-iteration
// BEHIND batch 0 (anti-phase) so every tagged poll is preceded by compute:
//   [prefetch A1(k-1)] B0 pollA1 | C0 B1 | C1 M0 M1 A0 |
__global__ __launch_bounds__(NP, 2) void emd_kernel(
    const float* __restrict__ a_mask, const float* __restrict__ pc_a,
    const float* __restrict__ b_mask, const float* __restrict__ pc_b,
    float2* __restrict__ parts, float2* __restrict__ rhob,
    float2* __restrict__ epi, float* __restrict__ out)
{
  const int rb = blockIdx.x;
  const int rg = rb & 15;
  const int b0 = rb >> 4;            // batch pair (b0, b0+16)
  const int t  = threadIdx.x;
  const int chunk = t & 15;          // 16 threads per row
  const int lrow  = t >> 4;          // local row 0..31
  const int grow  = rg*RPB + lrow;
  const int lane  = t & 63, wid = t >> 6;
  const int r_st  = t & 15;          // combine: stream index
  const int c_l   = t >> 4;          // combine: col within slice (0..31)
  const int gcol  = 32*rg + c_l;     // combine: global col

  __shared__ __align__(16) float rho_l[2][NP];  // exp(logv)
  __shared__ __align__(16) float bw_l[2][NP];   // col masses
  __shared__ __align__(16) float u_l[2][RPB];   // exp(logu)
  __shared__ __align__(16) float sm[NP];        // setup aw / epilogue scratch
  __shared__ float red[16];

  float4 eKreg[2][8];     // row slice: row=grow, cols 64*cc+4*chunk+e
  float  eKcol[2][RPB];   // col slice: col=t, rows rg*32+i
  float  aw_r[2], bw_t[2];
  float  hub0 = 0.f, hub1 = 0.f;

  // ================= setup: masses, huber, expK caches =================
  #pragma unroll
  for (int X = 0; X < 2; ++X) {
    const int b = b0 + 16*X;
    const float apt = a_mask[b*NP+t] * pc_a[((size_t)b*NP+t)*3+2];
    const float bpt = b_mask[b*NP+t] * pc_b[((size_t)b*NP+t)*3+2];
    float ra = apt, rv = bpt;
    #pragma unroll
    for (int o = 32; o; o >>= 1) { ra += __shfl_xor(ra, o); rv += __shfl_xor(rv, o); }
    if (lane == 0) { red[wid] = ra; red[8+wid] = rv; }
    __syncthreads();
    float asum = 0.f, bsum = 0.f;
    #pragma unroll
    for (int w = 0; w < 8; ++w) { asum += red[w]; bsum += red[8+w]; }
    const float e = asum - bsum, ae = fabsf(e);
    const float hub = (ae <= 1.f) ? 0.5f*e*e : (ae - 0.5f);
    if (X == 0) hub0 = hub; else hub1 = hub;
    sm[t]      = (apt > 0.f) ? apt/asum : 0.f;   // aw
    bw_l[X][t] = (bpt > 0.f) ? bpt/bsum : 0.f;
    __syncthreads();
    aw_r[X] = sm[grow];
    bw_t[X] = bw_l[X][t];
    const float ax = pc_a[((size_t)b*NP+grow)*3+0];
    const float ay = pc_a[((size_t)b*NP+grow)*3+1];
    const bool  va = aw_r[X] > 0.f;
    #pragma unroll
    for (int cc = 0; cc < 8; ++cc) {
      float r[4];
      #pragma unroll
      for (int e2 = 0; e2 < 4; ++e2) {
        const int col = 64*cc + 4*chunk + e2;
        const float bx = pc_b[((size_t)b*NP+col)*3+0];
        const float by = pc_b[((size_t)b*NP+col)*3+1];
        const bool  vb = bw_l[X][col] > 0.f;
        const float dx = ax-bx, dy = ay-by;
        const float d  = sqrtf(dx*dx + dy*dy + 1e-12f);
        r[e2] = (va && vb) ? __expf((-INVEPS)*d) : 1.f;   // K=0 for masked pairs
      }
      eKreg[X][cc] = make_float4(r[0], r[1], r[2], r[3]);
    }
    const float bx0 = pc_b[((size_t)b*NP+t)*3+0];
    const float by0 = pc_b[((size_t)b*NP+t)*3+1];
    const bool  vb0 = bw_t[X] > 0.f;
    #pragma unroll
    for (int i = 0; i < RPB; ++i) {
      const int row = rg*RPB + i;
      const float axi = pc_a[((size_t)b*NP+row)*3+0];  // wave-uniform -> scalar loads
      const float ayi = pc_a[((size_t)b*NP+row)*3+1];
      const bool  vai = sm[row] > 0.f;
      const float dx = axi-bx0, dy = ayi-by0;
      const float d  = sqrtf(dx*dx + dy*dy + 1e-12f);
      eKcol[X][i] = (vai && vb0) ? __expf((-INVEPS)*d) : 1.f;
    }
    rho_l[X][t] = 1.f;     // rho(0) = exp(logv=0) = 1
    __syncthreads();       // sm/red reuse safety + rho_l ready
  }

  // ================= main loop (anti-phase pipeline) =================
  for (int k = 1; k <= ITERS; ++k) {
    const float tagk = (float)k;
    const float tagp = (float)(k-1);
    const int par  = k & 1;
    const int parp = (k-1) & 1;

    // ---- prefetch A1(k-1): issue before B0 compute
    const float2* a1slot = rhob + ((size_t)parp*NB + (b0+16))*NP + t;
    float2 rq1;
    if (k > 1) rq1 = ld64(a1slot);

    // ---- B0: u0(k) = aw / sum_j ek*rho0(k-1)
    {
      const float4* r4p = (const float4*)rho_l[0];
      float dot = 0.f;
      #pragma unroll
      for (int cc = 0; cc < 8; ++cc) {
        const float4 g4 = r4p[16*cc + chunk];
        const float4 kk = eKreg[0][cc];
        dot += kk.x*g4.x + kk.y*g4.y + kk.z*g4.z + kk.w*g4.w;
      }
      #pragma unroll
      for (int o = 8; o; o >>= 1) dot += __shfl_xor(dot, o);
      if (chunk == 0) u_l[0][lrow] = aw_r[0] / fmaxf(dot, 1e-38f);
    }
    // ---- A1(k-1): poll rho1(k-1) -> rho_l1
    if (k > 1) {
      long long spins = 0;
      while (rq1.x != tagp) {
        __builtin_amdgcn_s_sleep(1);
        rq1 = ld64(a1slot);
        if (++spins > (1LL<<27)) break;   // fail visibly, never hang
      }
      rho_l[1][t] = rq1.y;
    }
    __syncthreads();   // u_l0 + rho_l1 ready

    // ---- C0: publish tagged col partials for batch 0
    {
      const float4* u4p = (const float4*)u_l[0];
      float sc = 0.f;
      #pragma unroll
      for (int i4 = 0; i4 < 8; ++i4) {
        const float4 uu = u4p[i4];
        sc += eKcol[0][4*i4+0]*uu.x + eKcol[0][4*i4+1]*uu.y
            + eKcol[0][4*i4+2]*uu.z + eKcol[0][4*i4+3]*uu.w;
      }
      st64(parts + (((size_t)par*NB + b0)*RG + rg)*NP + t, tagk, sc);
    }
    // ---- B1: u1(k) = aw / sum_j ek*rho1(k-1)
    {
      const float4* r4p = (const float4*)rho_l[1];
      float dot = 0.f;
      #pragma unroll
      for (int cc = 0; cc < 8; ++cc) {
        const float4 g4 = r4p[16*cc + chunk];
        const float4 kk = eKreg[1][cc];
        dot += kk.x*g4.x + kk.y*g4.y + kk.z*g4.z + kk.w*g4.w;
      }
      #pragma unroll
      for (int o = 8; o; o >>= 1) dot += __shfl_xor(dot, o);
      if (chunk == 0) u_l[1][lrow] = aw_r[1] / fmaxf(dot, 1e-38f);
    }
    __syncthreads();   // u_l1 ready

    // ---- C1: publish tagged col partials for batch 1
    {
      const float4* u4p = (const float4*)u_l[1];
      float sc = 0.f;
      #pragma unroll
      for (int i4 = 0; i4 < 8; ++i4) {
        const float4 uu = u4p[i4];
        sc += eKcol[1][4*i4+0]*uu.x + eKcol[1][4*i4+1]*uu.y
            + eKcol[1][4*i4+2]*uu.z + eKcol[1][4*i4+3]*uu.w;
      }
      st64(parts + (((size_t)par*NB + (b0+16))*RG + rg)*NP + t, tagk, sc);
    }

    // ---- M0+M1: combine slice [32rg,32rg+32), publish rho(k); issue both first
    {
      const float2* slot0 = parts + (((size_t)par*NB + b0)*RG + r_st)*NP + gcol;
      const float2* slot1 = parts + (((size_t)par*NB + (b0+16))*RG + r_st)*NP + gcol;
      float2 q0 = ld64(slot0);
      float2 q1 = ld64(slot1);
      long long spins = 0;
      while (q0.x != tagk) {
        __builtin_amdgcn_s_sleep(1);
        q0 = ld64(slot0);
        if (++spins > (1LL<<27)) break;
      }
      float S0 = q0.y;
      #pragma unroll
      for (int o = 8; o; o >>= 1) S0 += __shfl_xor(S0, o);
      if (r_st == 0)
        st64(rhob + ((size_t)par*NB + b0)*NP + gcol, tagk,
             bw_l[0][gcol] / fmaxf(S0, 1e-38f));
      spins = 0;
      while (q1.x != tagk) {
        __builtin_amdgcn_s_sleep(1);
        q1 = ld64(slot1);
        if (++spins > (1LL<<27)) break;
      }
      float S1 = q1.y;
      #pragma unroll
      for (int o = 8; o; o >>= 1) S1 += __shfl_xor(S1, o);
      if (r_st == 0)
        st64(rhob + ((size_t)par*NB + (b0+16))*NP + gcol, tagk,
             bw_l[1][gcol] / fmaxf(S1, 1e-38f));
    }

    // ---- A0: poll rho0(k) -> rho_l0
    {
      const float2* slot = rhob + ((size_t)par*NB + b0)*NP + t;
      float2 rq = ld64(slot);
      long long spins = 0;
      while (rq.x != tagk) {
        __builtin_amdgcn_s_sleep(1);
        rq = ld64(slot);
        if (++spins > (1LL<<27)) break;
      }
      rho_l[0][t] = rq.y;
    }
    __syncthreads();   // rho_l0(k) ready for next B0
  }

  // ---- drain: A1(ITERS) -> rho_l1
  {
    const float tagf = (float)ITERS;
    const float2* slot = rhob + ((size_t)(ITERS & 1)*NB + (b0+16))*NP + t;
    float2 rq = ld64(slot);
    long long spins = 0;
    while (rq.x != tagf) {
      __builtin_amdgcn_s_sleep(1);
      rq = ld64(slot);
      if (++spins > (1LL<<27)) break;
    }
    rho_l[1][t] = rq.y;
  }
  __syncthreads();

  // ---- epilogue: ot partial = sum d^2 * u_i * ek * rho_j over my row slice
  float accX[2];
  #pragma unroll
  for (int X = 0; X < 2; ++X) {
    const float ur = u_l[X][lrow];                  // u(50)
    const float4* r4p = (const float4*)rho_l[X];    // rho(50)
    float acc = 0.f;
    #pragma unroll
    for (int cc = 0; cc < 8; ++cc) {
      const float4 g4 = r4p[16*cc + chunk];
      const float4 kk = eKreg[X][cc];
      const float ek[4] = {kk.x, kk.y, kk.z, kk.w};
      const float vv[4] = {g4.x, g4.y, g4.z, g4.w};
      #pragma unroll
      for (int e2 = 0; e2 < 4; ++e2) {
        const float lk = __logf(fmaxf(ek[e2], 1e-38f));  // d = -EPS*lk; masked: lk=0 -> d2=0
        const float d2 = (EPSV*lk)*(EPSV*lk);
        const float v  = d2 * ur * ek[e2] * vv[e2];
        acc += (ek[e2] > 0.f) ? v : 0.f;
      }
    }
    accX[X] = acc;
  }
  // block-reduce each batch, publish tagged epi, rg==0 gathers
  float s0 = 0.f, s1 = 0.f;
  sm[t] = accX[0];
  __syncthreads();
  if (t < 64) {
    float v = 0.f;
    #pragma unroll
    for (int q = 0; q < 8; ++q) v += sm[t*8+q];
    #pragma unroll
    for (int o = 32; o; o >>= 1) v += __shfl_xor(v, o);
    s0 = v;
  }
  __syncthreads();
  sm[t] = accX[1];
  __syncthreads();
  if (t < 64) {
    float v = 0.f;
    #pragma unroll
    for (int q = 0; q < 8; ++q) v += sm[t*8+q];
    #pragma unroll
    for (int o = 32; o; o >>= 1) v += __shfl_xor(v, o);
    s1 = v;
  }
  if (t == 0) {
    st64(epi + (size_t)b0*RG + rg,      51.f, s0);
    st64(epi + (size_t)(b0+16)*RG + rg, 51.f, s1);
  }
  if (rg == 0 && t < 32) {     // gather: 16 lanes per batch, poll + shfl-reduce
    const int X = t >> 4, r = t & 15;
    const int b = b0 + 16*X;
    float2 pr;
    long long spins = 0;
    do {
      pr = ld64(epi + (size_t)b*RG + r);
      if (pr.x == 51.f) break;
      __builtin_amdgcn_s_sleep(1);
    } while (++spins < (1LL<<27));
    float v = pr.y;
    #pragma unroll
    for (int o = 8; o; o >>= 1) v += __shfl_xor(v, o);
    if (r == 0) out[b] = v + ((X == 0) ? hub0 : hub1);
  }
}

extern "C" void kernel_launch(void* const* d_in, const int* in_sizes, int n_in,
                              void* d_out, int out_size, void* d_ws, size_t ws_size,
                              hipStream_t stream) {
  const float* a_mask = (const float*)d_in[0];
  const float* pc_a   = (const float*)d_in[1];
  const float* b_mask = (const float*)d_in[2];
  const float* pc_b   = (const float*)d_in[3];
  float* out = (float*)d_out;
  float2* parts = (float2*)d_ws;            // 4 MiB
  float2* rhob  = parts + N_PARTS;          // + 256 KiB
  float2* epi   = rhob + N_RHOB;            // + 4 KiB
  (void)in_sizes; (void)n_in; (void)out_size; (void)ws_size;

  emd_kernel<<<NB*RG/2, NP, 0, stream>>>(a_mask, pc_a, b_mask, pc_b,
                                         parts, rhob, epi, out);
}